// Round 12
// baseline (365.789 us; speedup 1.0000x reference)
//
#include <hip/hip_runtime.h>

// Performer (FAVOR+) encoder block, bf16 MFMA pipeline. Round 12:
//  - r11 consolidation + fkv_reduce fused into favor_num (block-local
//    reduction of f32 partials, identical summation order -> same bits)
// B=32 L=1024 HID=512 H=8 DH=64 FF=2048, N=32768 tokens.

#define DI __device__ __forceinline__
#define AS1 __attribute__((address_space(1)))
#define AS3 __attribute__((address_space(3)))
#define GLD16(g, l) __builtin_amdgcn_global_load_lds((const AS1 void*)(g), (AS3 void*)(l), 16, 0, 0)

typedef __attribute__((ext_vector_type(8))) short bf16x8;
typedef __attribute__((ext_vector_type(4))) float f32x4;

DI float b2f(short s){ unsigned int u = ((unsigned int)(unsigned short)s) << 16; float f; __builtin_memcpy(&f, &u, 4); return f; }
DI short f2b(float f){ unsigned int u; __builtin_memcpy(&u, &f, 4); u += 0x7fffu + ((u >> 16) & 1u); return (short)(u >> 16); }

constexpr int Ll = 1024;
constexpr int SPLIT = 16384;

// ---------------- unified prep: x->bf16, weight transposes, bias pack ----------------
__global__ __launch_bounds__(256) void k_prep(
    const float* __restrict__ x, short* __restrict__ xb,
    const float* __restrict__ Wq, const float* __restrict__ Wk,
    const float* __restrict__ Wv, const float* __restrict__ Wo,
    short* __restrict__ wqkvT, short* __restrict__ woT,
    const float* __restrict__ W1, short* __restrict__ w1T,
    const float* __restrict__ W2, short* __restrict__ w2T,
    const float* __restrict__ bq, const float* __restrict__ bk,
    const float* __restrict__ bv, float* __restrict__ bqkv)
{
  int bid = blockIdx.x;
  if (bid < 8192) {
    long i = (long)bid * 256 + threadIdx.x;
    const float4* p = (const float4*)x + i * 2;
    float4 a = p[0], b = p[1];
    bf16x8 o;
    o[0]=f2b(a.x); o[1]=f2b(a.y); o[2]=f2b(a.z); o[3]=f2b(a.w);
    o[4]=f2b(b.x); o[5]=f2b(b.y); o[6]=f2b(b.z); o[7]=f2b(b.w);
    *((bf16x8*)xb + i) = o;
    return;
  }
  bid -= 8192;
  if (bid < 3072) {
    __shared__ float t[32][33];
    const float* in; short* out; int R, C, bx, by;
    if (bid < 1024) {
      int z = bid >> 8, ti = bid & 255;
      bx = ti & 15; by = ti >> 4; R = 512; C = 512;
      in  = z == 0 ? Wq : z == 1 ? Wk : z == 2 ? Wv : Wo;
      out = z == 0 ? wqkvT : z == 1 ? wqkvT + 512 * 512 : z == 2 ? wqkvT + 1024 * 512 : woT;
    } else if (bid < 2048) {
      int ti = bid - 1024; bx = ti & 63; by = ti >> 6; R = 512; C = 2048; in = W1; out = w1T;
    } else {
      int ti = bid - 2048; bx = ti & 15; by = ti >> 4; R = 2048; C = 512; in = W2; out = w2T;
    }
    int c0 = bx * 32, r0 = by * 32;
    int xx = threadIdx.x & 31, yy = threadIdx.x >> 5;
    #pragma unroll
    for (int j = 0; j < 4; ++j) t[yy + 8*j][xx] = in[(long)(r0 + yy + 8*j) * C + c0 + xx];
    __syncthreads();
    #pragma unroll
    for (int j = 0; j < 4; ++j) out[(long)(c0 + yy + 8*j) * R + r0 + xx] = f2b(t[xx][yy + 8*j]);
    return;
  }
  bid -= 3072;
  int i = bid * 256 + threadIdx.x;
  if (i < 512) bqkv[i] = bq[i];
  else if (i < 1024) bqkv[i] = bk[i - 512];
  else if (i < 1536) bqkv[i] = bv[i - 1024];
}

// ---------------- 256x256 bf16 MFMA GEMM, 8 waves, dbuf LDS, 1 barrier/K-tile ----
// LDS (128 KiB): A[buf][half][128][64] | B[buf][half][128][64]; 16B slot s of
// row r holds global chunk s^(r&7) (involution; conflict-free ds_read_b128).
// EPI: 0=QKV(phi) 1=attn-out(+bo+xb->bf16) 2=FFN1(relu,row-split) 3=FFN2(+b2+oQ in-place)
template<int EPI, int KD>
__global__ __launch_bounds__(512, 2) void k_gemm256(
    const short* __restrict__ A0, const short* __restrict__ A1,
    const short* __restrict__ BT, int NT,
    const float* __restrict__ bias, const short* __restrict__ residX,
    short* __restrict__ oQ, short* __restrict__ oK, short* __restrict__ oV,
    short* __restrict__ o1)
{
  __shared__ short lds[65536];              // 128 KiB
  const int tid = threadIdx.x;
  const int w = tid >> 6, lane = tid & 63;
  const int wm = w >> 2, wn = w & 3;        // 2M x 4N wave grid; per-wave out 128x64
  const int lg = lane >> 4, lr = lane & 15;
  const int lrow = lane >> 3, lslot = (lane & 7) ^ lrow;

  const int per = gridDim.x >> 3;
  const int wg = (blockIdx.x & 7) * per + (blockIdx.x >> 3);
  const long m0 = (long)(wg / NT) * 256, n0 = (long)(wg % NT) * 256;

  const short* Ause = A0;
  long mbase = m0;
  if (A1 != A0 && m0 >= SPLIT) { Ause = A1; mbase = m0 - SPLIT; }

  f32x4 acc[8][4];
  #pragma unroll
  for (int i = 0; i < 8; ++i)
    #pragma unroll
    for (int j = 0; j < 4; ++j) acc[i][j] = 0.f;

  auto stage_all = [&](int buf, int k0){
    #pragma unroll
    for (int half = 0; half < 2; ++half)
      #pragma unroll
      for (int q = 0; q < 2; ++q) {
        int r = w * 16 + q * 8;
        GLD16(Ause + (mbase + half * 128 + r + lrow) * KD + k0 + lslot * 8,
              (char*)lds + (buf * 16384 + half * 8192 + r * 64) * 2);
        GLD16(BT + (n0 + half * 128 + r + lrow) * KD + k0 + lslot * 8,
              (char*)lds + (32768 + buf * 16384 + half * 8192 + r * 64) * 2);
      }
  };

  constexpr int NKT = KD / 64;
  stage_all(0, 0);                          // prologue

  for (int kt = 0; kt < NKT; ++kt) {
    const int cur = kt & 1;
    __syncthreads();                        // drains buf[cur] staging; prior reads retired
    if (kt + 1 < NKT) stage_all(cur ^ 1, (kt + 1) * 64);

    const char* Ab = (const char*)lds + (cur * 16384 + wm * 8192) * 2;
    const char* Bb = (const char*)lds + (32768 + cur * 16384 + (wn >> 1) * 8192) * 2;

    bf16x8 fB[2][2][2];                     // [qc][j][kk] held for whole K-tile
    #pragma unroll
    for (int qc = 0; qc < 2; ++qc)
      #pragma unroll
      for (int j = 0; j < 2; ++j)
        #pragma unroll
        for (int kk = 0; kk < 2; ++kk) {
          int rb = (wn & 1) * 64 + qc * 32 + j * 16 + lr;
          fB[qc][j][kk] = *(const bf16x8*)(Bb + rb * 128 + ((kk * 64 + lg * 16) ^ ((rb & 7) << 4)));
        }
    #pragma unroll
    for (int qr = 0; qr < 2; ++qr) {
      bf16x8 fA[4][2];
      #pragma unroll
      for (int i = 0; i < 4; ++i)
        #pragma unroll
        for (int kk = 0; kk < 2; ++kk) {
          int ra = qr * 64 + i * 16 + lr;
          fA[i][kk] = *(const bf16x8*)(Ab + ra * 128 + ((kk * 64 + lg * 16) ^ ((ra & 7) << 4)));
        }
      __builtin_amdgcn_s_setprio(1);
      #pragma unroll
      for (int i = 0; i < 4; ++i)
        #pragma unroll
        for (int qc = 0; qc < 2; ++qc)
          #pragma unroll
          for (int j = 0; j < 2; ++j)
            #pragma unroll
            for (int kk = 0; kk < 2; ++kk)
              acc[qr * 4 + i][qc * 2 + j] =
                __builtin_amdgcn_mfma_f32_16x16x32_bf16(fA[i][kk], fB[qc][j][kk], acc[qr * 4 + i][qc * 2 + j], 0, 0, 0);
      __builtin_amdgcn_s_setprio(0);
    }
  }

  #pragma unroll
  for (int fr = 0; fr < 8; ++fr)
    #pragma unroll
    for (int fc = 0; fc < 4; ++fc)
      #pragma unroll
      for (int r = 0; r < 4; ++r) {
        int grow = (int)m0 + wm * 128 + fr * 16 + lg * 4 + r;  // C/D: row=(lane>>4)*4+reg
        int gcol = (int)n0 + wn * 64 + fc * 16 + lr;           //      col=lane&15
        float v = acc[fr][fc][r];
        if constexpr (EPI == 0) {
          v += bias[gcol];
          int which = gcol >> 9, hd = gcol & 511, h = hd >> 6, d = hd & 63;
          int b = grow >> 10, l = grow & 1023;
          long o = ((long)(b * 8 + h) * 1024 + l) * 64 + d;
          if (which == 2) oV[o] = f2b(v);
          else { float p = fmaxf(v, 0.f) + 1e-3f; if (which) oK[o] = f2b(p); else oQ[o] = f2b(p); }
        } else if constexpr (EPI == 1) {
          v += bias[gcol] + b2f(residX[(long)grow * 512 + gcol]);
          oQ[(long)grow * 512 + gcol] = f2b(v);
        } else if constexpr (EPI == 2) {
          v = fmaxf(v + bias[gcol], 0.f);
          if (grow < SPLIT) oQ[(long)grow * 2048 + gcol] = f2b(v);
          else              o1[(long)(grow - SPLIT) * 2048 + gcol] = f2b(v);
        } else {
          long idx = (long)grow * 512 + gcol;
          v += bias[gcol] + b2f(oQ[idx]);
          oQ[idx] = f2b(v);
        }
      }
}

// ---------------- FAVOR kv partials: chunk c sums l in [c*256, c*256+256) ----------------
__global__ __launch_bounds__(256) void k_fkv_part(const short* __restrict__ kp, const short* __restrict__ vb,
                                                  float* __restrict__ kvp, float* __restrict__ ksp)
{
  constexpr int LS = 72;
  __shared__ short kps[64 * LS];
  __shared__ short vps[64 * LS];
  int bh = blockIdx.x & 255, c = blockIdx.x >> 8;
  const short* kpp = kp + (long)bh * Ll * 64;
  const short* vpp = vb + (long)bh * Ll * 64;
  int tid = threadIdx.x;
  int mb = (tid & 15) * 4, db = (tid >> 4) * 4;
  float acc[4][4];
  float ks[4] = {0.f, 0.f, 0.f, 0.f};
  #pragma unroll
  for (int i = 0; i < 4; ++i)
    #pragma unroll
    for (int j = 0; j < 4; ++j) acc[i][j] = 0.f;

  for (int l0 = c * 256; l0 < c * 256 + 256; l0 += 64) {
    __syncthreads();
    #pragma unroll
    for (int s = 0; s < 2; ++s) {
      int idx = tid + s * 256;
      int row = idx >> 3, c8 = idx & 7;
      *(bf16x8*)(&kps[row * LS + c8 * 8]) = *(const bf16x8*)(kpp + (long)(l0 + row) * 64 + c8 * 8);
      *(bf16x8*)(&vps[row * LS + c8 * 8]) = *(const bf16x8*)(vpp + (long)(l0 + row) * 64 + c8 * 8);
    }
    __syncthreads();
    #pragma unroll 4
    for (int l = 0; l < 64; ++l) {
      short4 ka = *(const short4*)(&kps[l * LS + mb]);
      short4 va = *(const short4*)(&vps[l * LS + db]);
      float kf[4] = {b2f(ka.x), b2f(ka.y), b2f(ka.z), b2f(ka.w)};
      float vf[4] = {b2f(va.x), b2f(va.y), b2f(va.z), b2f(va.w)};
      if (tid < 16) { ks[0] += kf[0]; ks[1] += kf[1]; ks[2] += kf[2]; ks[3] += kf[3]; }
      #pragma unroll
      for (int i = 0; i < 4; ++i)
        #pragma unroll
        for (int j = 0; j < 4; ++j) acc[i][j] += kf[i] * vf[j];
    }
  }
  float* kout = kvp + (long)c * 1048576 + (long)bh * 4096;
  #pragma unroll
  for (int i = 0; i < 4; ++i)
    #pragma unroll
    for (int j = 0; j < 4; ++j)
      kout[(db + j) * 64 + mb + i] = acc[i][j];
  if (tid < 16) {
    #pragma unroll
    for (int i = 0; i < 4; ++i) ksp[(long)c * 16384 + bh * 64 + mb + i] = ks[i];
  }
}

// ---------------- FAVOR: attn = (qp @ kv)/den, with fused partial reduction ----------------
__global__ __launch_bounds__(256) void k_favor_num(const short* __restrict__ qp, const float* __restrict__ kvp,
                                                   const float* __restrict__ ksp, short* __restrict__ attn)
{
  constexpr int LS = 72;
  __shared__ short Qs[128 * 64];
  __shared__ short kvs[64 * LS];
  __shared__ float part[256];
  __shared__ float den[128];
  __shared__ float ksums[64];
  int bh = blockIdx.x >> 3, lt = blockIdx.x & 7;
  int b = bh >> 3, h = bh & 7;
  const short* qpp = qp + ((long)bh * Ll + lt * 128) * 64;
  int tid = threadIdx.x;
  int wave = tid >> 6, lane = tid & 63;
  int lrow = lane >> 3, lslot = (lane & 7) ^ lrow;

  #pragma unroll
  for (int s = 0; s < 4; ++s) {       // Q tile 128x64 via gload_lds
    int rs = (s * 4 + wave) * 8;
    GLD16(qpp + (long)(rs + lrow) * 64 + lslot * 8, &Qs[rs * 64]);
  }
  { // reduce kv partials: 16 elems per thread, same add order as old k_fkv_reduce
    const float* p0 = kvp + (long)bh * 4096;
    int g0 = tid * 16;                // row = tid>>2, cols (tid&3)*16 .. +16
    int row = g0 >> 6, col = g0 & 63;
    bf16x8 o0, o1;
    #pragma unroll
    for (int e = 0; e < 16; ++e) {
      int g = g0 + e;
      float s = p0[g] + p0[g + 1048576] + p0[g + 2 * 1048576] + p0[g + 3 * 1048576];
      if (e < 8) o0[e] = f2b(s); else o1[e - 8] = f2b(s);
    }
    *(bf16x8*)(&kvs[row * LS + col]) = o0;
    *(bf16x8*)(&kvs[row * LS + col + 8]) = o1;
    if (tid < 64)
      ksums[tid] = ksp[bh * 64 + tid] + ksp[16384 + bh * 64 + tid]
                 + ksp[2 * 16384 + bh * 64 + tid] + ksp[3 * 16384 + bh * 64 + tid];
  }
  __syncthreads();
  { // den partial: 2 threads per row, 32 features each (reads swizzled Qs)
    int r = tid >> 1, half = tid & 1;
    const float* kss = ksums + half * 32;
    float s = 0.f;
    #pragma unroll
    for (int c = 0; c < 4; ++c) {
      int cc = half * 4 + c;
      bf16x8 v = *(const bf16x8*)((const char*)Qs + r * 128 + ((cc * 16) ^ ((r & 7) << 4)));
      #pragma unroll
      for (int j = 0; j < 8; ++j) s += b2f(v[j]) * kss[c * 8 + j];
    }
    part[tid] = s;
  }
  __syncthreads();
  if (tid < 128) den[tid] = part[2 * tid] + part[2 * tid + 1];
  __syncthreads();

  int wr = wave >> 1, wc = wave & 1;
  int lg = lane >> 4, lr = lane & 15;
  f32x4 acc[4][2];
  #pragma unroll
  for (int i = 0; i < 4; ++i) { acc[i][0] = 0.f; acc[i][1] = 0.f; }
  #pragma unroll
  for (int kk = 0; kk < 2; ++kk) {
    bf16x8 af[4], bfr[2];
    #pragma unroll
    for (int i = 0; i < 4; ++i) {
      int ra = wr * 64 + i * 16 + lr;
      af[i] = *(const bf16x8*)((const char*)Qs + ra * 128 + ((kk * 64 + lg * 16) ^ ((ra & 7) << 4)));
    }
    #pragma unroll
    for (int j = 0; j < 2; ++j)
      bfr[j] = *(const bf16x8*)(&kvs[(wc * 32 + j * 16 + lr) * LS + kk * 32 + lg * 8]);
    #pragma unroll
    for (int i = 0; i < 4; ++i)
      #pragma unroll
      for (int j = 0; j < 2; ++j)
        acc[i][j] = __builtin_amdgcn_mfma_f32_16x16x32_bf16(af[i], bfr[j], acc[i][j], 0, 0, 0);
  }
  #pragma unroll
  for (int i = 0; i < 4; ++i)
    #pragma unroll
    for (int j = 0; j < 2; ++j)
      #pragma unroll
      for (int r = 0; r < 4; ++r) {
        int rl = wr * 64 + i * 16 + lg * 4 + r;
        int d  = wc * 32 + j * 16 + lr;
        int t  = b * Ll + lt * 128 + rl;
        attn[(long)t * 512 + h * 64 + d] = f2b(acc[i][j][r] / den[rl]);
      }
}

// ---------------- LayerNorm, bf16 in -> bf16 out ----------------
__global__ __launch_bounds__(256) void k_ln_bb(const short* __restrict__ in, const float* __restrict__ sc,
                                               const float* __restrict__ bi, short* __restrict__ ob)
{
  int row = blockIdx.x * 4 + (threadIdx.x >> 6);
  int lane = threadIdx.x & 63;
  bf16x8 v = *((const bf16x8*)(in + (long)row * 512) + lane);
  float e[8];
  #pragma unroll
  for (int j = 0; j < 8; ++j) e[j] = b2f(v[j]);
  float s = 0.f, s2 = 0.f;
  #pragma unroll
  for (int j = 0; j < 8; ++j) { s += e[j]; s2 += e[j] * e[j]; }
  #pragma unroll
  for (int off = 32; off; off >>= 1) { s += __shfl_xor(s, off); s2 += __shfl_xor(s2, off); }
  float mu = s * (1.f / 512.f);
  float var = s2 * (1.f / 512.f) - mu * mu;
  float rstd = rsqrtf(var + 1e-6f);
  int c0 = lane * 8;
  bf16x8 o;
  #pragma unroll
  for (int j = 0; j < 8; ++j) o[j] = f2b((e[j] - mu) * rstd * sc[c0 + j] + bi[c0 + j]);
  *((bf16x8*)(ob + (long)row * 512) + lane) = o;
}

// ---------------- LayerNorm, bf16 in -> f32 out ----------------
__global__ __launch_bounds__(256) void k_ln_bf(const short* __restrict__ in, const float* __restrict__ sc,
                                               const float* __restrict__ bi, float* __restrict__ of)
{
  int row = blockIdx.x * 4 + (threadIdx.x >> 6);
  int lane = threadIdx.x & 63;
  bf16x8 v = *((const bf16x8*)(in + (long)row * 512) + lane);
  float e[8];
  #pragma unroll
  for (int j = 0; j < 8; ++j) e[j] = b2f(v[j]);
  float s = 0.f, s2 = 0.f;
  #pragma unroll
  for (int j = 0; j < 8; ++j) { s += e[j]; s2 += e[j] * e[j]; }
  #pragma unroll
  for (int off = 32; off; off >>= 1) { s += __shfl_xor(s, off); s2 += __shfl_xor(s2, off); }
  float mu = s * (1.f / 512.f);
  float var = s2 * (1.f / 512.f) - mu * mu;
  float rstd = rsqrtf(var + 1e-6f);
  int c0 = lane * 8;
  float o0[4], o1[4];
  #pragma unroll
  for (int j = 0; j < 4; ++j) {
    o0[j] = (e[j]     - mu) * rstd * sc[c0 + j]     + bi[c0 + j];
    o1[j] = (e[4 + j] - mu) * rstd * sc[c0 + 4 + j] + bi[c0 + 4 + j];
  }
  *(float4*)(of + (long)row * 512 + c0)     = (float4){o0[0], o0[1], o0[2], o0[3]};
  *(float4*)(of + (long)row * 512 + c0 + 4) = (float4){o1[0], o1[1], o1[2], o1[3]};
}

extern "C" void kernel_launch(void* const* d_in, const int* in_sizes, int n_in,
                              void* d_out, int out_size, void* d_ws, size_t ws_size,
                              hipStream_t stream)
{
  const float* x   = (const float*)d_in[0];
  const float* Wq  = (const float*)d_in[1];
  const float* bq  = (const float*)d_in[2];
  const float* Wk  = (const float*)d_in[3];
  const float* bk  = (const float*)d_in[4];
  const float* Wv  = (const float*)d_in[5];
  const float* bv  = (const float*)d_in[6];
  const float* Wo  = (const float*)d_in[7];
  const float* bo  = (const float*)d_in[8];
  const float* g1  = (const float*)d_in[9];
  const float* be1 = (const float*)d_in[10];
  const float* W1  = (const float*)d_in[11];
  const float* b1  = (const float*)d_in[12];
  const float* W2  = (const float*)d_in[13];
  const float* b2  = (const float*)d_in[14];
  const float* g2  = (const float*)d_in[15];
  const float* be2 = (const float*)d_in[16];
  float* out = (float*)d_out;

  const long MB = 1024L * 1024L;
  char* ws = (char*)d_ws;
  short* qp    = (short*)(ws + 0 * MB);
  short* kp    = (short*)(ws + 32 * MB);
  short* vb    = (short*)(ws + 64 * MB);
  short* attn  = (short*)(ws + 32 * MB);
  short* hb    = (short*)(ws + 0 * MB);
  short* hpreB = (short*)(ws + 64 * MB);
  short* ffa0  = (short*)(ws + 32 * MB);
  short* wqkvT = (short*)(ws + 96 * MB);
  short* woT   = (short*)(ws + 98 * MB);
  short* w1T   = (short*)(ws + 99 * MB);
  short* w2T   = (short*)(ws + 101 * MB);
  float* bqkv  = (float*)(ws + 103 * MB);

  short* xb   = (short*)d_out;
  float* kvp  = (float*)((char*)d_out + 32 * MB);   // 16 MiB [4][256][64][64] f32
  float* ksp  = (float*)((char*)d_out + 48 * MB);   // 256 KiB [4][256][64] f32
  short* ffa1 = (short*)d_out;

  k_prep<<<11270, 256, 0, stream>>>(x, xb, Wq, Wk, Wv, Wo, wqkvT, woT,
                                    W1, w1T, W2, w2T, bq, bk, bv, bqkv);

  k_gemm256<0, 512><<<768, 512, 0, stream>>>(xb, xb, wqkvT, 6, bqkv, nullptr, qp, kp, vb, nullptr);
  k_fkv_part<<<1024, 256, 0, stream>>>(kp, vb, kvp, ksp);
  k_favor_num<<<2048, 256, 0, stream>>>(qp, kvp, ksp, attn);
  k_gemm256<1, 512><<<256, 512, 0, stream>>>(attn, attn, woT, 2, bo, xb, hpreB, nullptr, nullptr, nullptr);
  k_ln_bb<<<8192, 256, 0, stream>>>(hpreB, g1, be1, hb);
  k_gemm256<2, 512><<<1024, 512, 0, stream>>>(hb, hb, w1T, 8, b1, nullptr, ffa0, nullptr, nullptr, ffa1);
  k_gemm256<3, 2048><<<256, 512, 0, stream>>>(ffa0, ffa1, w2T, 2, b2, nullptr, hb, nullptr, nullptr, nullptr);
  k_ln_bf<<<8192, 256, 0, stream>>>(hb, g2, be2, out);
}

// Round 13
// 351.757 us; speedup vs baseline: 1.0399x; 1.0399x over previous
//
#include <hip/hip_runtime.h>

// Performer (FAVOR+) encoder block, bf16 MFMA pipeline. Round 13 = r11 revert
// (r12's fkv_reduce-into-favor_num fusion regressed +10us: 8x redundant
// partial re-reduction per (b,h). Dedicated reduce kernel restored.)
//  - GEMM: r5 K-loop (best measured: FFN1 81us) — 128 KiB dbuf,
//    __launch_bounds__(512,2), sync -> stage(next buf) -> ds_read+MFMA, 16x16x32
//  - r8 prep fusion, bf16 residual, FFN row-split, in-place FFN2, bf16 LNs
// B=32 L=1024 HID=512 H=8 DH=64 FF=2048, N=32768 tokens.

#define DI __device__ __forceinline__
#define AS1 __attribute__((address_space(1)))
#define AS3 __attribute__((address_space(3)))
#define GLD16(g, l) __builtin_amdgcn_global_load_lds((const AS1 void*)(g), (AS3 void*)(l), 16, 0, 0)

typedef __attribute__((ext_vector_type(8))) short bf16x8;
typedef __attribute__((ext_vector_type(4))) float f32x4;

DI float b2f(short s){ unsigned int u = ((unsigned int)(unsigned short)s) << 16; float f; __builtin_memcpy(&f, &u, 4); return f; }
DI short f2b(float f){ unsigned int u; __builtin_memcpy(&u, &f, 4); u += 0x7fffu + ((u >> 16) & 1u); return (short)(u >> 16); }

constexpr int Ll = 1024;
constexpr int SPLIT = 16384;

// ---------------- unified prep: x->bf16, weight transposes, bias pack ----------------
__global__ __launch_bounds__(256) void k_prep(
    const float* __restrict__ x, short* __restrict__ xb,
    const float* __restrict__ Wq, const float* __restrict__ Wk,
    const float* __restrict__ Wv, const float* __restrict__ Wo,
    short* __restrict__ wqkvT, short* __restrict__ woT,
    const float* __restrict__ W1, short* __restrict__ w1T,
    const float* __restrict__ W2, short* __restrict__ w2T,
    const float* __restrict__ bq, const float* __restrict__ bk,
    const float* __restrict__ bv, float* __restrict__ bqkv)
{
  int bid = blockIdx.x;
  if (bid < 8192) {
    long i = (long)bid * 256 + threadIdx.x;
    const float4* p = (const float4*)x + i * 2;
    float4 a = p[0], b = p[1];
    bf16x8 o;
    o[0]=f2b(a.x); o[1]=f2b(a.y); o[2]=f2b(a.z); o[3]=f2b(a.w);
    o[4]=f2b(b.x); o[5]=f2b(b.y); o[6]=f2b(b.z); o[7]=f2b(b.w);
    *((bf16x8*)xb + i) = o;
    return;
  }
  bid -= 8192;
  if (bid < 3072) {
    __shared__ float t[32][33];
    const float* in; short* out; int R, C, bx, by;
    if (bid < 1024) {
      int z = bid >> 8, ti = bid & 255;
      bx = ti & 15; by = ti >> 4; R = 512; C = 512;
      in  = z == 0 ? Wq : z == 1 ? Wk : z == 2 ? Wv : Wo;
      out = z == 0 ? wqkvT : z == 1 ? wqkvT + 512 * 512 : z == 2 ? wqkvT + 1024 * 512 : woT;
    } else if (bid < 2048) {
      int ti = bid - 1024; bx = ti & 63; by = ti >> 6; R = 512; C = 2048; in = W1; out = w1T;
    } else {
      int ti = bid - 2048; bx = ti & 15; by = ti >> 4; R = 2048; C = 512; in = W2; out = w2T;
    }
    int c0 = bx * 32, r0 = by * 32;
    int xx = threadIdx.x & 31, yy = threadIdx.x >> 5;
    #pragma unroll
    for (int j = 0; j < 4; ++j) t[yy + 8*j][xx] = in[(long)(r0 + yy + 8*j) * C + c0 + xx];
    __syncthreads();
    #pragma unroll
    for (int j = 0; j < 4; ++j) out[(long)(c0 + yy + 8*j) * R + r0 + xx] = f2b(t[xx][yy + 8*j]);
    return;
  }
  bid -= 3072;
  int i = bid * 256 + threadIdx.x;
  if (i < 512) bqkv[i] = bq[i];
  else if (i < 1024) bqkv[i] = bk[i - 512];
  else if (i < 1536) bqkv[i] = bv[i - 1024];
}

// ---------------- 256x256 bf16 MFMA GEMM, 8 waves, dbuf LDS, 1 barrier/K-tile ----
// LDS (128 KiB): A[buf][half][128][64] | B[buf][half][128][64]; 16B slot s of
// row r holds global chunk s^(r&7) (involution; conflict-free ds_read_b128).
// EPI: 0=QKV(phi) 1=attn-out(+bo+xb->bf16) 2=FFN1(relu,row-split) 3=FFN2(+b2+oQ in-place)
template<int EPI, int KD>
__global__ __launch_bounds__(512, 2) void k_gemm256(
    const short* __restrict__ A0, const short* __restrict__ A1,
    const short* __restrict__ BT, int NT,
    const float* __restrict__ bias, const short* __restrict__ residX,
    short* __restrict__ oQ, short* __restrict__ oK, short* __restrict__ oV,
    short* __restrict__ o1)
{
  __shared__ short lds[65536];              // 128 KiB
  const int tid = threadIdx.x;
  const int w = tid >> 6, lane = tid & 63;
  const int wm = w >> 2, wn = w & 3;        // 2M x 4N wave grid; per-wave out 128x64
  const int lg = lane >> 4, lr = lane & 15;
  const int lrow = lane >> 3, lslot = (lane & 7) ^ lrow;

  const int per = gridDim.x >> 3;
  const int wg = (blockIdx.x & 7) * per + (blockIdx.x >> 3);
  const long m0 = (long)(wg / NT) * 256, n0 = (long)(wg % NT) * 256;

  const short* Ause = A0;
  long mbase = m0;
  if (A1 != A0 && m0 >= SPLIT) { Ause = A1; mbase = m0 - SPLIT; }

  f32x4 acc[8][4];
  #pragma unroll
  for (int i = 0; i < 8; ++i)
    #pragma unroll
    for (int j = 0; j < 4; ++j) acc[i][j] = 0.f;

  auto stage_all = [&](int buf, int k0){
    #pragma unroll
    for (int half = 0; half < 2; ++half)
      #pragma unroll
      for (int q = 0; q < 2; ++q) {
        int r = w * 16 + q * 8;
        GLD16(Ause + (mbase + half * 128 + r + lrow) * KD + k0 + lslot * 8,
              (char*)lds + (buf * 16384 + half * 8192 + r * 64) * 2);
        GLD16(BT + (n0 + half * 128 + r + lrow) * KD + k0 + lslot * 8,
              (char*)lds + (32768 + buf * 16384 + half * 8192 + r * 64) * 2);
      }
  };

  constexpr int NKT = KD / 64;
  stage_all(0, 0);                          // prologue

  for (int kt = 0; kt < NKT; ++kt) {
    const int cur = kt & 1;
    __syncthreads();                        // drains buf[cur] staging; prior reads retired
    if (kt + 1 < NKT) stage_all(cur ^ 1, (kt + 1) * 64);

    const char* Ab = (const char*)lds + (cur * 16384 + wm * 8192) * 2;
    const char* Bb = (const char*)lds + (32768 + cur * 16384 + (wn >> 1) * 8192) * 2;

    bf16x8 fB[2][2][2];                     // [qc][j][kk] held for whole K-tile
    #pragma unroll
    for (int qc = 0; qc < 2; ++qc)
      #pragma unroll
      for (int j = 0; j < 2; ++j)
        #pragma unroll
        for (int kk = 0; kk < 2; ++kk) {
          int rb = (wn & 1) * 64 + qc * 32 + j * 16 + lr;
          fB[qc][j][kk] = *(const bf16x8*)(Bb + rb * 128 + ((kk * 64 + lg * 16) ^ ((rb & 7) << 4)));
        }
    #pragma unroll
    for (int qr = 0; qr < 2; ++qr) {
      bf16x8 fA[4][2];
      #pragma unroll
      for (int i = 0; i < 4; ++i)
        #pragma unroll
        for (int kk = 0; kk < 2; ++kk) {
          int ra = qr * 64 + i * 16 + lr;
          fA[i][kk] = *(const bf16x8*)(Ab + ra * 128 + ((kk * 64 + lg * 16) ^ ((ra & 7) << 4)));
        }
      __builtin_amdgcn_s_setprio(1);
      #pragma unroll
      for (int i = 0; i < 4; ++i)
        #pragma unroll
        for (int qc = 0; qc < 2; ++qc)
          #pragma unroll
          for (int j = 0; j < 2; ++j)
            #pragma unroll
            for (int kk = 0; kk < 2; ++kk)
              acc[qr * 4 + i][qc * 2 + j] =
                __builtin_amdgcn_mfma_f32_16x16x32_bf16(fA[i][kk], fB[qc][j][kk], acc[qr * 4 + i][qc * 2 + j], 0, 0, 0);
      __builtin_amdgcn_s_setprio(0);
    }
  }

  #pragma unroll
  for (int fr = 0; fr < 8; ++fr)
    #pragma unroll
    for (int fc = 0; fc < 4; ++fc)
      #pragma unroll
      for (int r = 0; r < 4; ++r) {
        int grow = (int)m0 + wm * 128 + fr * 16 + lg * 4 + r;  // C/D: row=(lane>>4)*4+reg
        int gcol = (int)n0 + wn * 64 + fc * 16 + lr;           //      col=lane&15
        float v = acc[fr][fc][r];
        if constexpr (EPI == 0) {
          v += bias[gcol];
          int which = gcol >> 9, hd = gcol & 511, h = hd >> 6, d = hd & 63;
          int b = grow >> 10, l = grow & 1023;
          long o = ((long)(b * 8 + h) * 1024 + l) * 64 + d;
          if (which == 2) oV[o] = f2b(v);
          else { float p = fmaxf(v, 0.f) + 1e-3f; if (which) oK[o] = f2b(p); else oQ[o] = f2b(p); }
        } else if constexpr (EPI == 1) {
          v += bias[gcol] + b2f(residX[(long)grow * 512 + gcol]);
          oQ[(long)grow * 512 + gcol] = f2b(v);
        } else if constexpr (EPI == 2) {
          v = fmaxf(v + bias[gcol], 0.f);
          if (grow < SPLIT) oQ[(long)grow * 2048 + gcol] = f2b(v);
          else              o1[(long)(grow - SPLIT) * 2048 + gcol] = f2b(v);
        } else {
          long idx = (long)grow * 512 + gcol;
          v += bias[gcol] + b2f(oQ[idx]);
          oQ[idx] = f2b(v);
        }
      }
}

// ---------------- FAVOR kv partials: chunk c sums l in [c*256, c*256+256) ----------------
__global__ __launch_bounds__(256) void k_fkv_part(const short* __restrict__ kp, const short* __restrict__ vb,
                                                  float* __restrict__ kvp, float* __restrict__ ksp)
{
  constexpr int LS = 72;
  __shared__ short kps[64 * LS];
  __shared__ short vps[64 * LS];
  int bh = blockIdx.x & 255, c = blockIdx.x >> 8;
  const short* kpp = kp + (long)bh * Ll * 64;
  const short* vpp = vb + (long)bh * Ll * 64;
  int tid = threadIdx.x;
  int mb = (tid & 15) * 4, db = (tid >> 4) * 4;
  float acc[4][4];
  float ks[4] = {0.f, 0.f, 0.f, 0.f};
  #pragma unroll
  for (int i = 0; i < 4; ++i)
    #pragma unroll
    for (int j = 0; j < 4; ++j) acc[i][j] = 0.f;

  for (int l0 = c * 256; l0 < c * 256 + 256; l0 += 64) {
    __syncthreads();
    #pragma unroll
    for (int s = 0; s < 2; ++s) {
      int idx = tid + s * 256;
      int row = idx >> 3, c8 = idx & 7;
      *(bf16x8*)(&kps[row * LS + c8 * 8]) = *(const bf16x8*)(kpp + (long)(l0 + row) * 64 + c8 * 8);
      *(bf16x8*)(&vps[row * LS + c8 * 8]) = *(const bf16x8*)(vpp + (long)(l0 + row) * 64 + c8 * 8);
    }
    __syncthreads();
    #pragma unroll 4
    for (int l = 0; l < 64; ++l) {
      short4 ka = *(const short4*)(&kps[l * LS + mb]);
      short4 va = *(const short4*)(&vps[l * LS + db]);
      float kf[4] = {b2f(ka.x), b2f(ka.y), b2f(ka.z), b2f(ka.w)};
      float vf[4] = {b2f(va.x), b2f(va.y), b2f(va.z), b2f(va.w)};
      if (tid < 16) { ks[0] += kf[0]; ks[1] += kf[1]; ks[2] += kf[2]; ks[3] += kf[3]; }
      #pragma unroll
      for (int i = 0; i < 4; ++i)
        #pragma unroll
        for (int j = 0; j < 4; ++j) acc[i][j] += kf[i] * vf[j];
    }
  }
  float* kout = kvp + (long)c * 1048576 + (long)bh * 4096;
  #pragma unroll
  for (int i = 0; i < 4; ++i)
    #pragma unroll
    for (int j = 0; j < 4; ++j)
      kout[(db + j) * 64 + mb + i] = acc[i][j];
  if (tid < 16) {
    #pragma unroll
    for (int i = 0; i < 4; ++i) ksp[(long)c * 16384 + bh * 64 + mb + i] = ks[i];
  }
}

__global__ __launch_bounds__(256) void k_fkv_reduce(const float* __restrict__ kvp, const float* __restrict__ ksp,
                                                    short* __restrict__ kvt, float* __restrict__ ksum)
{
  int g = blockIdx.x * 256 + threadIdx.x;
  float s = kvp[g] + kvp[g + 1048576] + kvp[g + 2 * 1048576] + kvp[g + 3 * 1048576];
  kvt[g] = f2b(s);
  if (g < 16384)
    ksum[g] = ksp[g] + ksp[g + 16384] + ksp[g + 2 * 16384] + ksp[g + 3 * 16384];
}

// ---------------- FAVOR: attn = (qp @ kv)/den ----------------
__global__ __launch_bounds__(256) void k_favor_num(const short* __restrict__ qp, const short* __restrict__ kvt,
                                                   const float* __restrict__ ksum, short* __restrict__ attn)
{
  constexpr int LS = 72;
  __shared__ short Qs[128 * 64];
  __shared__ short kvs[64 * LS];
  __shared__ float part[256];
  __shared__ float den[128];
  int bh = blockIdx.x >> 3, lt = blockIdx.x & 7;
  int b = bh >> 3, h = bh & 7;
  const short* qpp = qp + ((long)bh * Ll + lt * 128) * 64;
  int tid = threadIdx.x;
  int wave = tid >> 6, lane = tid & 63;
  int lrow = lane >> 3, lslot = (lane & 7) ^ lrow;

  #pragma unroll
  for (int s = 0; s < 4; ++s) {
    int rs = (s * 4 + wave) * 8;
    GLD16(qpp + (long)(rs + lrow) * 64 + lslot * 8, &Qs[rs * 64]);
  }
  #pragma unroll
  for (int s = 0; s < 2; ++s) {
    int idx = tid + s * 256;
    int row = idx >> 3, c8 = idx & 7;
    *(bf16x8*)(&kvs[row * LS + c8 * 8]) = *(const bf16x8*)(kvt + (long)bh * 4096 + row * 64 + c8 * 8);
  }
  __syncthreads();
  {
    int r = tid >> 1, half = tid & 1;
    const float* kss = ksum + bh * 64 + half * 32;
    float s = 0.f;
    #pragma unroll
    for (int c = 0; c < 4; ++c) {
      int cc = half * 4 + c;
      bf16x8 v = *(const bf16x8*)((const char*)Qs + r * 128 + ((cc * 16) ^ ((r & 7) << 4)));
      #pragma unroll
      for (int j = 0; j < 8; ++j) s += b2f(v[j]) * kss[c * 8 + j];
    }
    part[tid] = s;
  }
  __syncthreads();
  if (tid < 128) den[tid] = part[2 * tid] + part[2 * tid + 1];
  __syncthreads();

  int wr = wave >> 1, wc = wave & 1;
  int lg = lane >> 4, lr = lane & 15;
  f32x4 acc[4][2];
  #pragma unroll
  for (int i = 0; i < 4; ++i) { acc[i][0] = 0.f; acc[i][1] = 0.f; }
  #pragma unroll
  for (int kk = 0; kk < 2; ++kk) {
    bf16x8 af[4], bfr[2];
    #pragma unroll
    for (int i = 0; i < 4; ++i) {
      int ra = wr * 64 + i * 16 + lr;
      af[i] = *(const bf16x8*)((const char*)Qs + ra * 128 + ((kk * 64 + lg * 16) ^ ((ra & 7) << 4)));
    }
    #pragma unroll
    for (int j = 0; j < 2; ++j)
      bfr[j] = *(const bf16x8*)(&kvs[(wc * 32 + j * 16 + lr) * LS + kk * 32 + lg * 8]);
    #pragma unroll
    for (int i = 0; i < 4; ++i)
      #pragma unroll
      for (int j = 0; j < 2; ++j)
        acc[i][j] = __builtin_amdgcn_mfma_f32_16x16x32_bf16(af[i], bfr[j], acc[i][j], 0, 0, 0);
  }
  #pragma unroll
  for (int i = 0; i < 4; ++i)
    #pragma unroll
    for (int j = 0; j < 2; ++j)
      #pragma unroll
      for (int r = 0; r < 4; ++r) {
        int rl = wr * 64 + i * 16 + lg * 4 + r;
        int d  = wc * 32 + j * 16 + lr;
        int t  = b * Ll + lt * 128 + rl;
        attn[(long)t * 512 + h * 64 + d] = f2b(acc[i][j][r] / den[rl]);
      }
}

// ---------------- LayerNorm, bf16 in -> bf16 out ----------------
__global__ __launch_bounds__(256) void k_ln_bb(const short* __restrict__ in, const float* __restrict__ sc,
                                               const float* __restrict__ bi, short* __restrict__ ob)
{
  int row = blockIdx.x * 4 + (threadIdx.x >> 6);
  int lane = threadIdx.x & 63;
  bf16x8 v = *((const bf16x8*)(in + (long)row * 512) + lane);
  float e[8];
  #pragma unroll
  for (int j = 0; j < 8; ++j) e[j] = b2f(v[j]);
  float s = 0.f, s2 = 0.f;
  #pragma unroll
  for (int j = 0; j < 8; ++j) { s += e[j]; s2 += e[j] * e[j]; }
  #pragma unroll
  for (int off = 32; off; off >>= 1) { s += __shfl_xor(s, off); s2 += __shfl_xor(s2, off); }
  float mu = s * (1.f / 512.f);
  float var = s2 * (1.f / 512.f) - mu * mu;
  float rstd = rsqrtf(var + 1e-6f);
  int c0 = lane * 8;
  bf16x8 o;
  #pragma unroll
  for (int j = 0; j < 8; ++j) o[j] = f2b((e[j] - mu) * rstd * sc[c0 + j] + bi[c0 + j]);
  *((bf16x8*)(ob + (long)row * 512) + lane) = o;
}

// ---------------- LayerNorm, bf16 in -> f32 out ----------------
__global__ __launch_bounds__(256) void k_ln_bf(const short* __restrict__ in, const float* __restrict__ sc,
                                               const float* __restrict__ bi, float* __restrict__ of)
{
  int row = blockIdx.x * 4 + (threadIdx.x >> 6);
  int lane = threadIdx.x & 63;
  bf16x8 v = *((const bf16x8*)(in + (long)row * 512) + lane);
  float e[8];
  #pragma unroll
  for (int j = 0; j < 8; ++j) e[j] = b2f(v[j]);
  float s = 0.f, s2 = 0.f;
  #pragma unroll
  for (int j = 0; j < 8; ++j) { s += e[j]; s2 += e[j] * e[j]; }
  #pragma unroll
  for (int off = 32; off; off >>= 1) { s += __shfl_xor(s, off); s2 += __shfl_xor(s2, off); }
  float mu = s * (1.f / 512.f);
  float var = s2 * (1.f / 512.f) - mu * mu;
  float rstd = rsqrtf(var + 1e-6f);
  int c0 = lane * 8;
  float o0[4], o1[4];
  #pragma unroll
  for (int j = 0; j < 4; ++j) {
    o0[j] = (e[j]     - mu) * rstd * sc[c0 + j]     + bi[c0 + j];
    o1[j] = (e[4 + j] - mu) * rstd * sc[c0 + 4 + j] + bi[c0 + 4 + j];
  }
  *(float4*)(of + (long)row * 512 + c0)     = (float4){o0[0], o0[1], o0[2], o0[3]};
  *(float4*)(of + (long)row * 512 + c0 + 4) = (float4){o1[0], o1[1], o1[2], o1[3]};
}

extern "C" void kernel_launch(void* const* d_in, const int* in_sizes, int n_in,
                              void* d_out, int out_size, void* d_ws, size_t ws_size,
                              hipStream_t stream)
{
  const float* x   = (const float*)d_in[0];
  const float* Wq  = (const float*)d_in[1];
  const float* bq  = (const float*)d_in[2];
  const float* Wk  = (const float*)d_in[3];
  const float* bk  = (const float*)d_in[4];
  const float* Wv  = (const float*)d_in[5];
  const float* bv  = (const float*)d_in[6];
  const float* Wo  = (const float*)d_in[7];
  const float* bo  = (const float*)d_in[8];
  const float* g1  = (const float*)d_in[9];
  const float* be1 = (const float*)d_in[10];
  const float* W1  = (const float*)d_in[11];
  const float* b1  = (const float*)d_in[12];
  const float* W2  = (const float*)d_in[13];
  const float* b2  = (const float*)d_in[14];
  const float* g2  = (const float*)d_in[15];
  const float* be2 = (const float*)d_in[16];
  float* out = (float*)d_out;

  const long MB = 1024L * 1024L;
  char* ws = (char*)d_ws;
  short* qp    = (short*)(ws + 0 * MB);
  short* kp    = (short*)(ws + 32 * MB);
  short* vb    = (short*)(ws + 64 * MB);
  short* attn  = (short*)(ws + 32 * MB);
  short* hb    = (short*)(ws + 0 * MB);
  short* hpreB = (short*)(ws + 64 * MB);
  short* ffa0  = (short*)(ws + 32 * MB);
  short* wqkvT = (short*)(ws + 96 * MB);
  short* woT   = (short*)(ws + 98 * MB);
  short* w1T   = (short*)(ws + 99 * MB);
  short* w2T   = (short*)(ws + 101 * MB);
  short* kvt   = (short*)(ws + 103 * MB);
  float* ksum  = (float*)(ws + 105 * MB);
  float* bqkv  = (float*)(ws + 105 * MB + 65536);

  short* xb   = (short*)d_out;
  float* kvp  = (float*)((char*)d_out + 32 * MB);
  float* ksp  = (float*)((char*)d_out + 48 * MB);
  short* ffa1 = (short*)d_out;

  k_prep<<<11270, 256, 0, stream>>>(x, xb, Wq, Wk, Wv, Wo, wqkvT, woT,
                                    W1, w1T, W2, w2T, bq, bk, bv, bqkv);

  k_gemm256<0, 512><<<768, 512, 0, stream>>>(xb, xb, wqkvT, 6, bqkv, nullptr, qp, kp, vb, nullptr);
  k_fkv_part<<<1024, 256, 0, stream>>>(kp, vb, kvp, ksp);
  k_fkv_reduce<<<4096, 256, 0, stream>>>(kvp, ksp, kvt, ksum);
  k_favor_num<<<2048, 256, 0, stream>>>(qp, kvt, ksum, attn);
  k_gemm256<1, 512><<<256, 512, 0, stream>>>(attn, attn, woT, 2, bo, xb, hpreB, nullptr, nullptr, nullptr);
  k_ln_bb<<<8192, 256, 0, stream>>>(hpreB, g1, be1, hb);
  k_gemm256<2, 512><<<1024, 512, 0, stream>>>(hb, hb, w1T, 8, b1, nullptr, ffa0, nullptr, nullptr, ffa1);
  k_gemm256<3, 2048><<<256, 512, 0, stream>>>(ffa0, ffa1, w2T, 2, b2, nullptr, hb, nullptr, nullptr, nullptr);
  k_ln_bf<<<8192, 256, 0, stream>>>(hb, g2, be2, out);
}